// Round 5
// baseline (3209.205 us; speedup 1.0000x reference)
//
#include <hip/hip_runtime.h>
#include <stdint.h>

// SpikingLinearLayer: 20-step LIF over [512 batch, 2048 out] driven by
// binary (10% dense) input spikes x[20,512,2048] through W[2048,2048].
//
// EXACT i8-MFMA path: W -> 4 limbs of q = round(W*2^31) (3 balanced
// base-256 digits + top); x in {0,1}. C = (sum_j 256^j C_j) * 2^-31,
// C_j exact int32 i8 GEMMs; int64 recombine + fp64 scale exact.
// QUANTIZATION FROZEN.
//
// Gemm history: R18 128x128 150us@53%; R19 256x128 syncthreads dbuf
// 147us@52%; R22 counted-vmcnt NEUTRAL 153us; R23 256x256 1blk/CU
// FAILED 180us@41% (occupancy loss kills cross-block overlap).
// LESSON: all 16-wave/CU configs sit ~150 regardless of bytes/sync;
// occupancy is sacred. ALSO: total-gemm = ~177us every round -- the
// prep/lif side is as big as the GEMM (floors ~82us -> ~95us slack).
//
// R24: (1) limb-PAIRING: block computes limbs {2lp,2lp+1} sharing one
// A tile (A staged once per (mtb,ntc), staged 1.97->1.31 GB; LDS
// reads/mfma -25%) at UNCHANGED 2 blk/CU 16 waves/CU. Epilogue
// combines exactly: int32 = C_even + (C_odd<<8) (|.|<67M, exact).
// K-loop byte-identical R19 __syncthreads dbuf (measured best).
// (2) lif reads 2 int32 planes, tot = pA + (pB<<16) -- exact, half
// the loads. (3) prep_x LDS repack -> linear 16B stores.

#define STEPS  20
#define BATCH  512
#define DIM    2048

// ---- ws layout (MFMA path)
#define XQ_OFF   0ULL
#define WQ_OFF   20971520ULL          // xq: 80*32*8192
#define C_OFF    37748736ULL          // + wq: 4*16*32*8192

#define GLOBAL_AS __attribute__((address_space(1)))
#define LDS_AS    __attribute__((address_space(3)))

typedef int v4i  __attribute__((ext_vector_type(4)));
typedef int v16i __attribute__((ext_vector_type(16)));

// ============================ MFMA path ============================

// xq[mt<80][kc<32][w<4][mm<128][16] : byte = (x[m][k]!=0)
//   m = mt*128+mm, k = kc*64 + w*16 + j   (m = t*512+b natural order)
// R24: LDS repack -> linear coalesced 16B stores.
__global__ __launch_bounds__(256)
void prep_x_kernel(const float* __restrict__ x, char* __restrict__ wsb)
{
    __shared__ __align__(16) char pl[8192];
    const int bid = blockIdx.x;           // bid = mt*32 + kc
    const int kc = bid & 31, mt = bid >> 5;
    const int tid = threadIdx.x;
    char* outb = wsb + (size_t)bid * 8192;
#pragma unroll
    for (int it = 0; it < 8; ++it) {
        const int idx = it * 256 + tid;
        const int mm = idx >> 4;
        const int kk4 = (idx & 15) << 2;
        const float4 v = *reinterpret_cast<const float4*>(
            x + (size_t)(mt * 128 + mm) * DIM + kc * 64 + kk4);
        uchar4 o;
        o.x = (v.x != 0.0f); o.y = (v.y != 0.0f);
        o.z = (v.z != 0.0f); o.w = (v.w != 0.0f);
        *reinterpret_cast<uchar4*>(
            &pl[(((kk4 >> 4) * 128 + mm) << 4) + (kk4 & 15)]) = o;
    }
    __syncthreads();
#pragma unroll
    for (int rep = 0; rep < 2; ++rep) {
        const int off = (rep * 256 + tid) * 16;
        *reinterpret_cast<int4*>(outb + off) =
            *reinterpret_cast<const int4*>(&pl[off]);
    }
}

// wq[limb<4][nt<16][kc<32][w<4][nn<128][16] :
//   byte = digit_limb(round(W[o][k]*2^31)), o = nt*128+nn, k = kc*64+w*16+j
// digits staged in LDS, planes written out linearly (coalesced).
__global__ __launch_bounds__(256)
void prep_w_kernel(const float* __restrict__ W, char* __restrict__ wsb)
{
    __shared__ __align__(16) char pl[4][8192];
    const int bid = blockIdx.x;           // bid = nt*32 + kc
    const int kc = bid & 31, nt = bid >> 5;
    const int tid = threadIdx.x;
    char* wqb = wsb + WQ_OFF;
#pragma unroll
    for (int it = 0; it < 8; ++it) {
        const int idx = it * 256 + tid;
        const int nn = idx >> 4;
        const int kk4 = (idx & 15) << 2;
        const float4 v = *reinterpret_cast<const float4*>(
            W + (size_t)(nt * 128 + nn) * DIM + kc * 64 + kk4);
        int dg[4][4];
        const float* vp = &v.x;
#pragma unroll
        for (int c = 0; c < 4; ++c) {
            long long q = __double2ll_rn((double)vp[c] * 2147483648.0);
#pragma unroll
            for (int j = 0; j < 3; ++j) {
                int d = (int)(q & 255);
                if (d >= 128) d -= 256;        // balanced digit
                dg[c][j] = d;
                q = (q - d) >> 8;
            }
            dg[c][3] = (int)q;                 // |.| <= ~97 for |W| < 0.76
        }
        const int sub = (((kk4 >> 4) * 128 + nn) << 4) + (kk4 & 15);
#pragma unroll
        for (int j = 0; j < 4; ++j) {
            uchar4 o;
            o.x = (unsigned char)(dg[0][j] & 255);
            o.y = (unsigned char)(dg[1][j] & 255);
            o.z = (unsigned char)(dg[2][j] & 255);
            o.w = (unsigned char)(dg[3][j] & 255);
            *reinterpret_cast<uchar4*>(&pl[j][sub]) = o;
        }
    }
    __syncthreads();
#pragma unroll
    for (int j = 0; j < 4; ++j) {
        char* dst = wqb + ((size_t)((j * 16 + nt) * 32 + kc)) * 8192;
#pragma unroll
        for (int rep = 0; rep < 2; ++rep) {
            const int off = (rep * 256 + tid) * 16;
            *reinterpret_cast<int4*>(dst + off) =
                *reinterpret_cast<const int4*>(&pl[j][off]);
        }
    }
}

// C planes (int32): plane lp in {0,1} holds C_{2lp} + 256*C_{2lp+1}
// (exact in int32: |C_even| + 256|C_odd| <= 0.27M + 67M).
// R24 tile: 256(m) x 128(o) x limb-pair per block, 512 thr / 8 waves
// (wy=w&3 -> m-sub 64, wx=w>>2 -> o-sub 64); per wave 2x2 accs per
// limb = 8 accs. A = two xq planes (16 KB), B = wq planes of limbs
// 2lp,2lp+1 (16 KB) per kc; A shared across the pair (staged bytes
// 1.97 -> 1.31 GB). K-loop: R19's validated __syncthreads double
// buffer, 1 barrier per kc. Grid: lp slow, ntc mid, mtb FAST.
__global__ __launch_bounds__(512, 4)
void gemm_i8_kernel(const char* __restrict__ wsb_c, int* __restrict__ cp,
                    int nt0, int ntc_cnt, int no)
{
    __shared__ __align__(16) char lds[2][32768]; // [buf][A0 8K|A1 8K|BL 8K|BH 8K]

    const int bid = blockIdx.x;           // mtb fastest, ntc mid, lp slow
    const int mtb = bid % 40;
    const int rest = bid / 40;
    const int ntc = rest % ntc_cnt;
    const int lp  = rest / ntc_cnt;       // limb pair: limbs 2lp, 2lp+1

    const int tid = threadIdx.x;
    const int lane = tid & 63, w = tid >> 6;   // 8 waves
    const int kh = lane >> 5, ln = lane & 31;
    const int wy = w & 3, wx = w >> 2;

    const char* abase0 = wsb_c + XQ_OFF + ((size_t)(2 * mtb) * 32) * 8192;
    const char* abase1 = abase0 + (size_t)32 * 8192;
    const int nt = nt0 + ntc;
    const char* bbaseL = wsb_c + WQ_OFF
        + ((size_t)(((2 * lp) * 16 + nt) * 32)) * 8192;
    const char* bbaseH = wsb_c + WQ_OFF
        + ((size_t)(((2 * lp + 1) * 16 + nt) * 32)) * 8192;

    // A read: plane (wy>>1), 64-row block (wy&1) within 128
    const int atile = (wy >> 1) * 8192;
    const int aoffl = ((kh * 128) + (wy & 1) * 64 + ln) << 4;
    const int boff  = ((kh * 128) + wx * 64 + ln) << 4;
    const int stg = w * 1024 + (lane << 4);   // wave's 1 KB DMA slot

    v16i aL00, aL01, aL10, aL11, aH00, aH01, aH10, aH11;
#pragma unroll
    for (int r = 0; r < 16; ++r) {
        aL00[r] = 0; aL01[r] = 0; aL10[r] = 0; aL11[r] = 0;
        aH00[r] = 0; aH01[r] = 0; aH10[r] = 0; aH11[r] = 0;
    }

    LDS_AS char* const lb0 = (LDS_AS char*)(&lds[0][0]);
    LDS_AS char* const lb1 = (LDS_AS char*)(&lds[1][0]);

    // stage kc-chunk kcv into buffer dstp (4 loads / wave)
#define STAGE(dstp, kcv) do {                                               \
        const size_t src_ = (size_t)(kcv) * 8192 + stg;                     \
        __builtin_amdgcn_global_load_lds(                                   \
            (const GLOBAL_AS void*)(abase0 + src_),                         \
            (LDS_AS void*)((dstp) + w * 1024), 16, 0, 0);                   \
        __builtin_amdgcn_global_load_lds(                                   \
            (const GLOBAL_AS void*)(abase1 + src_),                         \
            (LDS_AS void*)((dstp) + 8192 + w * 1024), 16, 0, 0);            \
        __builtin_amdgcn_global_load_lds(                                   \
            (const GLOBAL_AS void*)(bbaseL + src_),                         \
            (LDS_AS void*)((dstp) + 16384 + w * 1024), 16, 0, 0);           \
        __builtin_amdgcn_global_load_lds(                                   \
            (const GLOBAL_AS void*)(bbaseH + src_),                         \
            (LDS_AS void*)((dstp) + 24576 + w * 1024), 16, 0, 0);           \
    } while (0)

    // prologue: stage kc=0 into buf0
    STAGE(lb0, 0);

    for (int kc = 0; kc < 32; ++kc) {
        __syncthreads();   // drains prefetch for kc (issued one iter ago)
        const int cur = kc & 1;
        if (kc + 1 < 32) STAGE((kc & 1) ? lb0 : lb1, kc + 1);
        const char* A_  = (const char*)(&lds[cur][0]) + atile;
        const char* BL_ = (const char*)(&lds[cur][0]) + 16384;
        const char* BH_ = (const char*)(&lds[cur][0]) + 24576;
#pragma unroll
        for (int s = 0; s < 2; ++s) {
            const v4i a0 = *reinterpret_cast<const v4i*>(A_ + aoffl + s * 4096);
            const v4i a1 = *reinterpret_cast<const v4i*>(A_ + aoffl + 512 + s * 4096);
            const v4i bl0 = *reinterpret_cast<const v4i*>(BL_ + boff + s * 4096);
            const v4i bl1 = *reinterpret_cast<const v4i*>(BL_ + boff + 512 + s * 4096);
            const v4i bh0 = *reinterpret_cast<const v4i*>(BH_ + boff + s * 4096);
            const v4i bh1 = *reinterpret_cast<const v4i*>(BH_ + boff + 512 + s * 4096);
            aL00 = __builtin_amdgcn_mfma_i32_32x32x32_i8(a0, bl0, aL00, 0, 0, 0);
            aL01 = __builtin_amdgcn_mfma_i32_32x32x32_i8(a0, bl1, aL01, 0, 0, 0);
            aL10 = __builtin_amdgcn_mfma_i32_32x32x32_i8(a1, bl0, aL10, 0, 0, 0);
            aL11 = __builtin_amdgcn_mfma_i32_32x32x32_i8(a1, bl1, aL11, 0, 0, 0);
            aH00 = __builtin_amdgcn_mfma_i32_32x32x32_i8(a0, bh0, aH00, 0, 0, 0);
            aH01 = __builtin_amdgcn_mfma_i32_32x32x32_i8(a0, bh1, aH01, 0, 0, 0);
            aH10 = __builtin_amdgcn_mfma_i32_32x32x32_i8(a1, bh0, aH10, 0, 0, 0);
            aH11 = __builtin_amdgcn_mfma_i32_32x32x32_i8(a1, bh1, aH11, 0, 0, 0);
        }
    }
#undef STAGE

    // epilogue: C/D layout col=lane&31, row=(r&3)+8*(r>>2)+4*(lane>>5).
    // Combine the pair exactly: int32 = C_even + (C_odd << 8).
    int* cpl = cp + (size_t)lp * 10240 * no;
    const int m_base = mtb * 256 + wy * 64;
    const int o_base = ntc * 128 + wx * 64 + ln;
#pragma unroll
    for (int r = 0; r < 16; ++r) {
        const int row = (r & 3) + ((r >> 2) << 3) + (kh << 2);
        const size_t m0 = (size_t)(m_base + row) * no;
        const size_t m1 = (size_t)(m_base + 32 + row) * no;
        cpl[m0 + o_base]      = aL00[r] + (aH00[r] << 8);
        cpl[m0 + o_base + 32] = aL01[r] + (aH01[r] << 8);
        cpl[m1 + o_base]      = aL10[r] + (aH10[r] << 8);
        cpl[m1 + o_base + 32] = aL11[r] + (aH11[r] << 8);
    }
}

// LIF scan: exact int64 recombine of 2 int32 pair-planes
// (tot = pA + 2^16 pB = C0 + 256 C1 + 2^16 C2 + 2^24 C3), fp64 scale
// by 2^-31 (exact), reference op order.
__global__ __launch_bounds__(256)
void lif_kernel(const int* __restrict__ cp, float* __restrict__ out,
                int o0, int no, int shift)
{
    const int g = blockIdx.x * 256 + threadIdx.x;
    const int b = g >> shift;                  // shift = log2(no/4)
    const int oq = g & ((1 << shift) - 1);
    const int o_local = oq << 2;
    const size_t plane = (size_t)10240 * no;

    const double A_M = 1.0 - 1.0 / 20.0;   // 0.95
    const double DTM = 1.0 / 20.0;         // 0.05
    const double A_S = 1.0 - 1.0 / 5.0;    // 0.8
    double V[4], I[4];
#pragma unroll
    for (int u = 0; u < 4; ++u) { V[u] = 0.0; I[u] = 0.0; }

#pragma unroll
    for (int t = 0; t < STEPS; ++t) {
        const size_t ix = (size_t)(t * BATCH + b) * no + o_local;
        const int4 cA = *reinterpret_cast<const int4*>(cp + ix);
        const int4 cB = *reinterpret_cast<const int4*>(cp + plane + ix);
        const int* pA = &cA.x; const int* pB = &cB.x;
        float4 s;
        float* sp = &s.x;
#pragma unroll
        for (int u = 0; u < 4; ++u) {
            const long long tot = (long long)pA[u]
                + ((long long)pB[u] << 16);
            const double val = (double)tot * 4.6566128730773926e-10; // 2^-31
            V[u] = A_M * V[u] + DTM * I[u];
            float sv = 0.0f;
            if (V[u] >= 1.0) { sv = 1.0f; V[u] = 0.0; }
            sp[u] = sv;
            I[u] = A_S * I[u] + val;
        }
        *reinterpret_cast<float4*>(
            out + (size_t)(t * BATCH + b) * DIM + o0 + o_local) = s;
    }
}

// ===================== fallback (R10 sparse path) =====================

#define B_TILE 2
#define O_TILE 256
#define NT     512
#define KT     32
#define NSLAB  (DIM / KT)
#define ROWB   1024

__global__ __launch_bounds__(256)
void transpose_kernel(const float* __restrict__ W, float* __restrict__ WT)
{
    __shared__ float tile[64][65];
    const int tid = threadIdx.x;
    const int c4 = (tid & 15) * 4;
    const int rr = tid >> 4;
    const int k0 = blockIdx.x * 64, o0 = blockIdx.y * 64;
#pragma unroll
    for (int i = 0; i < 64; i += 16) {
        const float4 v = *reinterpret_cast<const float4*>(
            W + (size_t)(o0 + rr + i) * DIM + k0 + c4);
        tile[c4 + 0][rr + i] = v.x;
        tile[c4 + 1][rr + i] = v.y;
        tile[c4 + 2][rr + i] = v.z;
        tile[c4 + 3][rr + i] = v.w;
    }
    __syncthreads();
#pragma unroll
    for (int i = 0; i < 64; i += 16) {
        float4 v;
        v.x = tile[rr + i][c4 + 0];
        v.y = tile[rr + i][c4 + 1];
        v.z = tile[rr + i][c4 + 2];
        v.w = tile[rr + i][c4 + 3];
        *reinterpret_cast<float4*>(
            WT + (size_t)(k0 + rr + i) * DIM + o0 + c4) = v;
    }
}

__global__ __launch_bounds__(NT, 6)
void snn_lif_kernel(const float* __restrict__ x,
                    const float* __restrict__ WT,
                    float* __restrict__ out)
{
    __shared__ __align__(16) float wlds[(KT * ROWB) / 4];

    const int tid  = threadIdx.x;
    const int lane = tid & 63;
    const int w    = tid >> 6;
    const int bl   = w & 1;
    const int tq   = w >> 1;
    const int o_blk = blockIdx.x & 7;
    const int b_blk = blockIdx.x >> 3;
    const int b  = b_blk * B_TILE + bl;
    const int o0 = o_blk * O_TILE;

    double acc[5][4];
#pragma unroll
    for (int tt = 0; tt < 5; ++tt)
#pragma unroll
        for (int u = 0; u < 4; ++u) acc[tt][u] = 0.0;

    const int kl = lane & 31;
    float xr[5];
#pragma unroll
    for (int m = 0; m < 5; ++m)
        xr[m] = x[((size_t)(tq * 5 + m) * BATCH + b) * DIM + kl];

    const char*   gb   = (const char*)wlds + (lane << 4);
    LDS_AS char*  ldsb = (LDS_AS char*)wlds;
    const float*  wsrc = WT + o0 + (lane << 2);

    for (int kt = 0; kt < NSLAB; ++kt) {
        const int k0 = kt * KT;
        __syncthreads();
#pragma unroll
        for (int it = 0; it < 4; ++it) {
            const int r = w + it * 8;
            __builtin_amdgcn_global_load_lds(
                (const GLOBAL_AS void*)(wsrc + (size_t)(k0 + r) * DIM),
                (LDS_AS void*)(ldsb + r * ROWB), 16, 0, 0);
        }
        unsigned mk[5];
#pragma unroll
        for (int m = 0; m < 5; ++m)
            mk[m] = (unsigned)__ballot(xr[m] != 0.0f);
        __syncthreads();
        if (kt + 1 < NSLAB) {
            const int k1 = k0 + KT;
#pragma unroll
            for (int m = 0; m < 5; ++m)
                xr[m] = x[((size_t)(tq * 5 + m) * BATCH + b) * DIM + k1 + kl];
        }
#pragma unroll
        for (int m = 0; m < 5; ++m) {
            unsigned msk = mk[m];
            while (msk & (msk - 1)) {
                const int r0 = __builtin_ctz(msk); msk &= msk - 1;
                const int r1 = __builtin_ctz(msk); msk &= msk - 1;
                const float4 va = *reinterpret_cast<const float4*>(gb + (r0 << 10));
                const float4 vb = *reinterpret_cast<const float4*>(gb + (r1 << 10));
                acc[m][0] += (double)va.x; acc[m][1] += (double)va.y;
                acc[m][2] += (double)va.z; acc[m][3] += (double)va.w;
                acc[m][0] += (double)vb.x; acc[m][1] += (double)vb.y;
                acc[m][2] += (double)vb.z; acc[m][3] += (double)vb.w;
            }
            if (msk) {
                const int r = __builtin_ctz(msk);
                const float4 wv = *reinterpret_cast<const float4*>(gb + (r << 10));
                acc[m][0] += (double)wv.x; acc[m][1] += (double)wv.y;
                acc[m][2] += (double)wv.z; acc[m][3] += (double)wv.w;
            }
        }
    }

    const double A_M = 1.0 - 1.0 / 20.0;
    const double DTM = 1.0 / 20.0;
    const double A_S = 1.0 - 1.0 / 5.0;

    __syncthreads();
    double2* hand = reinterpret_cast<double2*>(wlds);
    const int hbase = bl * 256 + (lane << 2);
    const size_t obase = (size_t)o0 + (lane << 2);

    for (int seg = 0; seg < 4; ++seg) {
        if (tq == seg) {
            double V[4], I[4];
            if (seg == 0) {
#pragma unroll
                for (int u = 0; u < 4; ++u) { V[u] = 0.0; I[u] = 0.0; }
            } else {
#pragma unroll
                for (int u = 0; u < 4; ++u) {
                    const double2 h = hand[hbase + u];
                    V[u] = h.x; I[u] = h.y;
                }
            }
#pragma unroll
            for (int tt = 0; tt < 5; ++tt) {
                const int t = seg * 5 + tt;
                float4 s;
                float* sp = &s.x;
#pragma unroll
                for (int u = 0; u < 4; ++u) {
                    V[u] = A_M * V[u] + DTM * I[u];
                    float sv = 0.0f;
                    if (V[u] >= 1.0) { sv = 1.0f; V[u] = 0.0; }
                    sp[u] = sv;
                    I[u] = A_S * I[u] + acc[tt][u];
                }
                *reinterpret_cast<float4*>(
                    out + ((size_t)t * BATCH + b) * DIM + obase) = s;
            }
            if (seg < 3) {
#pragma unroll
                for (int u = 0; u < 4; ++u)
                    hand[hbase + u] = make_double2(V[u], I[u]);
            }
        }
        __syncthreads();
    }
}

// ============================== host ==============================

extern "C" void kernel_launch(void* const* d_in, const int* in_sizes, int n_in,
                              void* d_out, int out_size, void* d_ws, size_t ws_size,
                              hipStream_t stream) {
    const float* x = (const float*)d_in[0];   // [20, 512, 2048] spikes
    const float* W = (const float*)d_in[1];   // [2048, 2048]
    float* out = (float*)d_out;               // [20, 512, 2048]
    char* wsb = (char*)d_ws;

    // choose the largest o-chunk whose int32 pair-planes fit in ws
    // need(no) = C_OFF + 2 * 10240 * no * 4 bytes (= 81920*no, unchanged)
    int no = 0, shift = 0;
    if      (ws_size >= C_OFF + 81920ULL * 2048) { no = 2048; shift = 9; }
    else if (ws_size >= C_OFF + 81920ULL * 1024) { no = 1024; shift = 8; }
    else if (ws_size >= C_OFF + 81920ULL * 512)  { no = 512;  shift = 7; }
    else if (ws_size >= C_OFF + 81920ULL * 256)  { no = 256;  shift = 6; }
    else if (ws_size >= C_OFF + 81920ULL * 128)  { no = 128;  shift = 5; }

    if (no) {
        // exact i8-MFMA path (R24 limb-paired; single-shot at no=2048)
        prep_x_kernel<<<2560, 256, 0, stream>>>(x, wsb);
        prep_w_kernel<<<512, 256, 0, stream>>>(W, wsb);
        int* cp = (int*)(wsb + C_OFF);
        const int ntc_cnt = no / 128;
        for (int nt0 = 0; nt0 < 16; nt0 += ntc_cnt) {
            gemm_i8_kernel<<<40 * ntc_cnt * 2, 512, 0, stream>>>(
                (const char*)wsb, cp, nt0, ntc_cnt, no);
            lif_kernel<<<no / 2, 256, 0, stream>>>(
                (const int*)cp, out, nt0 * 128, no, shift);
        }
    } else {
        // fallback: R10 sparse-gather pipeline (known-good, 580 us)
        float* WT = (float*)d_ws;
        dim3 tb(256);
        dim3 tg(DIM / 64, DIM / 64);
        transpose_kernel<<<tg, tb, 0, stream>>>(W, WT);
        const int grid = (BATCH / B_TILE) * (DIM / O_TILE);
        snn_lif_kernel<<<grid, NT, 0, stream>>>(x, WT, out);
    }
}

// Round 7
// 335.948 us; speedup vs baseline: 9.5527x; 9.5527x over previous
//
#include <hip/hip_runtime.h>
#include <stdint.h>

// SpikingLinearLayer: 20-step LIF over [512 batch, 2048 out] driven by
// binary (10% dense) input spikes x[20,512,2048] through W[2048,2048].
//
// EXACT i8-MFMA path (validated absmax 0.0): W -> 4 limbs of
// q = round(W*2^31) (3 balanced base-256 digits + top); x in {0,1}.
// C = (sum_j 256^j C_j) * 2^-31, C_j exact int32 i8 GEMMs; int64
// recombine + fp64 scale exact. QUANTIZATION FROZEN.
//
// Gemm history: R18 128x128 150us@53%; R19 256x128 syncthreads dbuf
// 147us@52% == SESSION BEST (total 324.4); R20 3-ring counted-vmcnt
// FAILED 171 (sched_barrier pin + dyn ring select); R22 clean counted
// vmcnt NEUTRAL 153; R23 256x256 1blk/CU FAILED 180 (occupancy);
// R24 limb-pair FAILED 3193us: launch_bounds(512,4) capped VGPR at
// 128 < the ~200 needed -> ALL 8 accs spilled to scratch (VGPR_Count
// 64, 15.8 GB HBM/dispatch). LESSONS: (a) occupancy 16 waves/CU is
// sacred; (b) reads/mfma is set by WAVE tile, and any bigger wave
// tile busts the 128-VGPR cap => gemm ~147us is structural here.
//
// R25: revert gemm/lif to R19 exactly. Side-kernel wins only:
// prep_x LDS repack (linear 16B stores, validated R24) and prep_x+
// prep_w FUSED into one launch (removes a launch gap; tiny prep_w
// rides concurrently with prep_x).
// (R26 = R25 resubmitted: round-6 bench was a GPU-acquisition
// timeout, kernel never ran.)

#define STEPS  20
#define BATCH  512
#define DIM    2048

// ---- ws layout (MFMA path)
#define XQ_OFF   0ULL
#define WQ_OFF   20971520ULL          // xq: 80*32*8192
#define C_OFF    37748736ULL          // + wq: 4*16*32*8192

#define GLOBAL_AS __attribute__((address_space(1)))
#define LDS_AS    __attribute__((address_space(3)))

typedef int v4i  __attribute__((ext_vector_type(4)));
typedef int v16i __attribute__((ext_vector_type(16)));

// ============================ MFMA path ============================

// Fused prep. Blocks [0,2560): xq; blocks [2560,3072): wq.
// xq[mt<80][kc<32][w<4][mm<128][16] : byte = (x[m][k]!=0)
//   m = mt*128+mm, k = kc*64 + w*16 + j   (m = t*512+b natural order)
// wq[limb<4][nt<16][kc<32][w<4][nn<128][16] :
//   byte = digit_limb(round(W[o][k]*2^31)), o = nt*128+nn
// Both paths stage digits/bytes in LDS and write planes out linearly
// (coalesced 16B stores).
__global__ __launch_bounds__(256)
void prep_xw_kernel(const float* __restrict__ x, const float* __restrict__ W,
                    char* __restrict__ wsb)
{
    __shared__ __align__(16) char pl[4][8192];
    const int bid = blockIdx.x;
    const int tid = threadIdx.x;

    if (bid < 2560) {
        // ---- x path ----
        const int kc = bid & 31, mt = bid >> 5;
        char* outb = wsb + (size_t)bid * 8192;
#pragma unroll
        for (int it = 0; it < 8; ++it) {
            const int idx = it * 256 + tid;
            const int mm = idx >> 4;
            const int kk4 = (idx & 15) << 2;
            const float4 v = *reinterpret_cast<const float4*>(
                x + (size_t)(mt * 128 + mm) * DIM + kc * 64 + kk4);
            uchar4 o;
            o.x = (v.x != 0.0f); o.y = (v.y != 0.0f);
            o.z = (v.z != 0.0f); o.w = (v.w != 0.0f);
            *reinterpret_cast<uchar4*>(
                &pl[0][(((kk4 >> 4) * 128 + mm) << 4) + (kk4 & 15)]) = o;
        }
        __syncthreads();
#pragma unroll
        for (int rep = 0; rep < 2; ++rep) {
            const int off = (rep * 256 + tid) * 16;
            *reinterpret_cast<int4*>(outb + off) =
                *reinterpret_cast<const int4*>(&pl[0][off]);
        }
    } else {
        // ---- w path ----
        const int b2 = bid - 2560;            // b2 = nt*32 + kc
        const int kc = b2 & 31, nt = b2 >> 5;
        char* wqb = wsb + WQ_OFF;
#pragma unroll
        for (int it = 0; it < 8; ++it) {
            const int idx = it * 256 + tid;
            const int nn = idx >> 4;
            const int kk4 = (idx & 15) << 2;
            const float4 v = *reinterpret_cast<const float4*>(
                W + (size_t)(nt * 128 + nn) * DIM + kc * 64 + kk4);
            int dg[4][4];
            const float* vp = &v.x;
#pragma unroll
            for (int c = 0; c < 4; ++c) {
                long long q = __double2ll_rn((double)vp[c] * 2147483648.0);
#pragma unroll
                for (int j = 0; j < 3; ++j) {
                    int d = (int)(q & 255);
                    if (d >= 128) d -= 256;        // balanced digit
                    dg[c][j] = d;
                    q = (q - d) >> 8;
                }
                dg[c][3] = (int)q;                 // |.| <= ~97 for |W| < 0.76
            }
            const int sub = (((kk4 >> 4) * 128 + nn) << 4) + (kk4 & 15);
#pragma unroll
            for (int j = 0; j < 4; ++j) {
                uchar4 o;
                o.x = (unsigned char)(dg[0][j] & 255);
                o.y = (unsigned char)(dg[1][j] & 255);
                o.z = (unsigned char)(dg[2][j] & 255);
                o.w = (unsigned char)(dg[3][j] & 255);
                *reinterpret_cast<uchar4*>(&pl[j][sub]) = o;
            }
        }
        __syncthreads();
#pragma unroll
        for (int j = 0; j < 4; ++j) {
            char* dst = wqb + ((size_t)((j * 16 + nt) * 32 + kc)) * 8192;
#pragma unroll
            for (int rep = 0; rep < 2; ++rep) {
                const int off = (rep * 256 + tid) * 16;
                *reinterpret_cast<int4*>(dst + off) =
                    *reinterpret_cast<const int4*>(&pl[j][off]);
            }
        }
    }
}

// C_j[m][o_local] int16 planes. R19 tile: 256x128 per limb, 512 thr /
// 8 waves (wy = w&3 -> m-sub of 64, wx = w>>2 -> n-sub of 64), each
// wave 2x2 of 32x32x32 i8 mfma. A = two stacked xq tiles (16 KB) + B
// 8 KB per kc; double-buffered DMA, 1 barrier per kc. Grid: limb slow,
// ntc mid, mtb FAST (B-tile sharers consecutive; xq LLC-resident).
__global__ __launch_bounds__(512, 4)
void gemm_i8_kernel(const char* __restrict__ wsb_c, short* __restrict__ cp,
                    int nt0, int ntc_cnt, int no)
{
    __shared__ __align__(16) char lds[2][24576];  // [buf][A0 8K|A1 8K|B 8K]

    const int bid = blockIdx.x;           // mtb fastest, ntc mid, limb slow
    const int mtb = bid % 40;
    const int rest = bid / 40;
    const int ntc = rest % ntc_cnt;
    const int limb = rest / ntc_cnt;

    const int tid = threadIdx.x;
    const int lane = tid & 63, w = tid >> 6;   // 8 waves
    const int kh = lane >> 5, ln = lane & 31;
    const int wy = w & 3, wx = w >> 2;

    const char* abase0 = wsb_c + XQ_OFF + ((size_t)(2 * mtb) * 32) * 8192;
    const char* abase1 = abase0 + (size_t)32 * 8192;
    const char* bbase = wsb_c + WQ_OFF
        + ((size_t)((limb * 16 + nt0 + ntc) * 32)) * 8192;

    // A read: tile (wy>>1), 64-row block (wy&1) within 128
    const int atile = (wy >> 1) * 8192;
    const int aoffl = ((kh * 128) + (wy & 1) * 64 + ln) << 4;
    const int boff  = ((kh * 128) + wx * 64 + ln) << 4;
    const int stg = w * 1024 + (lane << 4);   // wave's 1 KB DMA slot

    v16i acc00, acc01, acc10, acc11;
#pragma unroll
    for (int r = 0; r < 16; ++r) {
        acc00[r] = 0; acc01[r] = 0; acc10[r] = 0; acc11[r] = 0;
    }

    LDS_AS char* l0 = (LDS_AS char*)(&lds[0][0]);
    LDS_AS char* l1 = (LDS_AS char*)(&lds[1][0]);

    // prologue: stage kc=0 into buf0 (A0, A1, B: 1 KB per wave each)
    __builtin_amdgcn_global_load_lds(
        (const GLOBAL_AS void*)(abase0 + stg),
        (LDS_AS void*)(l0 + w * 1024), 16, 0, 0);
    __builtin_amdgcn_global_load_lds(
        (const GLOBAL_AS void*)(abase1 + stg),
        (LDS_AS void*)(l0 + 8192 + w * 1024), 16, 0, 0);
    __builtin_amdgcn_global_load_lds(
        (const GLOBAL_AS void*)(bbase + stg),
        (LDS_AS void*)(l0 + 16384 + w * 1024), 16, 0, 0);

    for (int kc = 0; kc < 32; ++kc) {
        __syncthreads();   // drains prefetch for kc (issued one iter ago)
        const int cur = kc & 1;
        if (kc + 1 < 32) {
            LDS_AS char* ldst = (kc & 1) ? l0 : l1;
            const size_t src = (size_t)(kc + 1) * 8192 + stg;
            __builtin_amdgcn_global_load_lds(
                (const GLOBAL_AS void*)(abase0 + src),
                (LDS_AS void*)(ldst + w * 1024), 16, 0, 0);
            __builtin_amdgcn_global_load_lds(
                (const GLOBAL_AS void*)(abase1 + src),
                (LDS_AS void*)(ldst + 8192 + w * 1024), 16, 0, 0);
            __builtin_amdgcn_global_load_lds(
                (const GLOBAL_AS void*)(bbase + src),
                (LDS_AS void*)(ldst + 16384 + w * 1024), 16, 0, 0);
        }
        const char* A = &lds[cur][atile];
        const char* B = &lds[cur][16384];
#pragma unroll
        for (int s = 0; s < 2; ++s) {
            const v4i a0 = *reinterpret_cast<const v4i*>(A + aoffl + s * 4096);
            const v4i a1 = *reinterpret_cast<const v4i*>(A + aoffl + 512 + s * 4096);
            const v4i b0 = *reinterpret_cast<const v4i*>(B + boff + s * 4096);
            const v4i b1 = *reinterpret_cast<const v4i*>(B + boff + 512 + s * 4096);
            acc00 = __builtin_amdgcn_mfma_i32_32x32x32_i8(a0, b0, acc00, 0, 0, 0);
            acc01 = __builtin_amdgcn_mfma_i32_32x32x32_i8(a0, b1, acc01, 0, 0, 0);
            acc10 = __builtin_amdgcn_mfma_i32_32x32x32_i8(a1, b0, acc10, 0, 0, 0);
            acc11 = __builtin_amdgcn_mfma_i32_32x32x32_i8(a1, b1, acc11, 0, 0, 0);
        }
    }

    // epilogue: C/D layout col=lane&31, row=(r&3)+8*(r>>2)+4*(lane>>5)
    short* cpl = cp + (size_t)limb * 10240 * no;
    const int m_base = mtb * 256 + wy * 64;
    const int o_base = ntc * 128 + wx * 64 + ln;
#pragma unroll
    for (int r = 0; r < 16; ++r) {
        const int row = (r & 3) + ((r >> 2) << 3) + (kh << 2);
        const size_t m0 = (size_t)(m_base + row) * no;
        const size_t m1 = (size_t)(m_base + 32 + row) * no;
        cpl[m0 + o_base]      = (short)acc00[r];
        cpl[m0 + o_base + 32] = (short)acc01[r];
        cpl[m1 + o_base]      = (short)acc10[r];
        cpl[m1 + o_base + 32] = (short)acc11[r];
    }
}

// LIF scan: exact int64 recombine of 4 int16 limb planes, fp64 scale
// by 2^-31 (exact), reference op order.
__global__ __launch_bounds__(256)
void lif_kernel(const short* __restrict__ cp, float* __restrict__ out,
                int o0, int no, int shift)
{
    const int g = blockIdx.x * 256 + threadIdx.x;
    const int b = g >> shift;                  // shift = log2(no/4)
    const int oq = g & ((1 << shift) - 1);
    const int o_local = oq << 2;
    const size_t plane = (size_t)10240 * no;

    const double A_M = 1.0 - 1.0 / 20.0;   // 0.95
    const double DTM = 1.0 / 20.0;         // 0.05
    const double A_S = 1.0 - 1.0 / 5.0;    // 0.8
    double V[4], I[4];
#pragma unroll
    for (int u = 0; u < 4; ++u) { V[u] = 0.0; I[u] = 0.0; }

#pragma unroll
    for (int t = 0; t < STEPS; ++t) {
        const size_t ix = (size_t)(t * BATCH + b) * no + o_local;
        const short4 c0 = *reinterpret_cast<const short4*>(cp + ix);
        const short4 c1 = *reinterpret_cast<const short4*>(cp + plane + ix);
        const short4 c2 = *reinterpret_cast<const short4*>(cp + 2 * plane + ix);
        const short4 c3 = *reinterpret_cast<const short4*>(cp + 3 * plane + ix);
        const short* p0 = &c0.x; const short* p1 = &c1.x;
        const short* p2 = &c2.x; const short* p3 = &c3.x;
        float4 s;
        float* sp = &s.x;
#pragma unroll
        for (int u = 0; u < 4; ++u) {
            const long long tot = (long long)p0[u]
                + ((long long)p1[u] << 8)
                + ((long long)p2[u] << 16)
                + ((long long)p3[u] << 24);
            const double val = (double)tot * 4.6566128730773926e-10; // 2^-31
            V[u] = A_M * V[u] + DTM * I[u];
            float sv = 0.0f;
            if (V[u] >= 1.0) { sv = 1.0f; V[u] = 0.0; }
            sp[u] = sv;
            I[u] = A_S * I[u] + val;
        }
        *reinterpret_cast<float4*>(
            out + (size_t)(t * BATCH + b) * DIM + o0 + o_local) = s;
    }
}

// ===================== fallback (R10 sparse path) =====================

#define B_TILE 2
#define O_TILE 256
#define NT     512
#define KT     32
#define NSLAB  (DIM / KT)
#define ROWB   1024

__global__ __launch_bounds__(256)
void transpose_kernel(const float* __restrict__ W, float* __restrict__ WT)
{
    __shared__ float tile[64][65];
    const int tid = threadIdx.x;
    const int c4 = (tid & 15) * 4;
    const int rr = tid >> 4;
    const int k0 = blockIdx.x * 64, o0 = blockIdx.y * 64;
#pragma unroll
    for (int i = 0; i < 64; i += 16) {
        const float4 v = *reinterpret_cast<const float4*>(
            W + (size_t)(o0 + rr + i) * DIM + k0 + c4);
        tile[c4 + 0][rr + i] = v.x;
        tile[c4 + 1][rr + i] = v.y;
        tile[c4 + 2][rr + i] = v.z;
        tile[c4 + 3][rr + i] = v.w;
    }
    __syncthreads();
#pragma unroll
    for (int i = 0; i < 64; i += 16) {
        float4 v;
        v.x = tile[rr + i][c4 + 0];
        v.y = tile[rr + i][c4 + 1];
        v.z = tile[rr + i][c4 + 2];
        v.w = tile[rr + i][c4 + 3];
        *reinterpret_cast<float4*>(
            WT + (size_t)(k0 + rr + i) * DIM + o0 + c4) = v;
    }
}

__global__ __launch_bounds__(NT, 6)
void snn_lif_kernel(const float* __restrict__ x,
                    const float* __restrict__ WT,
                    float* __restrict__ out)
{
    __shared__ __align__(16) float wlds[(KT * ROWB) / 4];

    const int tid  = threadIdx.x;
    const int lane = tid & 63;
    const int w    = tid >> 6;
    const int bl   = w & 1;
    const int tq   = w >> 1;
    const int o_blk = blockIdx.x & 7;
    const int b_blk = blockIdx.x >> 3;
    const int b  = b_blk * B_TILE + bl;
    const int o0 = o_blk * O_TILE;

    double acc[5][4];
#pragma unroll
    for (int tt = 0; tt < 5; ++tt)
#pragma unroll
        for (int u = 0; u < 4; ++u) acc[tt][u] = 0.0;

    const int kl = lane & 31;
    float xr[5];
#pragma unroll
    for (int m = 0; m < 5; ++m)
        xr[m] = x[((size_t)(tq * 5 + m) * BATCH + b) * DIM + kl];

    const char*   gb   = (const char*)wlds + (lane << 4);
    LDS_AS char*  ldsb = (LDS_AS char*)wlds;
    const float*  wsrc = WT + o0 + (lane << 2);

    for (int kt = 0; kt < NSLAB; ++kt) {
        const int k0 = kt * KT;
        __syncthreads();
#pragma unroll
        for (int it = 0; it < 4; ++it) {
            const int r = w + it * 8;
            __builtin_amdgcn_global_load_lds(
                (const GLOBAL_AS void*)(wsrc + (size_t)(k0 + r) * DIM),
                (LDS_AS void*)(ldsb + r * ROWB), 16, 0, 0);
        }
        unsigned mk[5];
#pragma unroll
        for (int m = 0; m < 5; ++m)
            mk[m] = (unsigned)__ballot(xr[m] != 0.0f);
        __syncthreads();
        if (kt + 1 < NSLAB) {
            const int k1 = k0 + KT;
#pragma unroll
            for (int m = 0; m < 5; ++m)
                xr[m] = x[((size_t)(tq * 5 + m) * BATCH + b) * DIM + k1 + kl];
        }
#pragma unroll
        for (int m = 0; m < 5; ++m) {
            unsigned msk = mk[m];
            while (msk & (msk - 1)) {
                const int r0 = __builtin_ctz(msk); msk &= msk - 1;
                const int r1 = __builtin_ctz(msk); msk &= msk - 1;
                const float4 va = *reinterpret_cast<const float4*>(gb + (r0 << 10));
                const float4 vb = *reinterpret_cast<const float4*>(gb + (r1 << 10));
                acc[m][0] += (double)va.x; acc[m][1] += (double)va.y;
                acc[m][2] += (double)va.z; acc[m][3] += (double)va.w;
                acc[m][0] += (double)vb.x; acc[m][1] += (double)vb.y;
                acc[m][2] += (double)vb.z; acc[m][3] += (double)vb.w;
            }
            if (msk) {
                const int r = __builtin_ctz(msk);
                const float4 wv = *reinterpret_cast<const float4*>(gb + (r << 10));
                acc[m][0] += (double)wv.x; acc[m][1] += (double)wv.y;
                acc[m][2] += (double)wv.z; acc[m][3] += (double)wv.w;
            }
        }
    }

    const double A_M = 1.0 - 1.0 / 20.0;
    const double DTM = 1.0 / 20.0;
    const double A_S = 1.0 - 1.0 / 5.0;

    __syncthreads();
    double2* hand = reinterpret_cast<double2*>(wlds);
    const int hbase = bl * 256 + (lane << 2);
    const size_t obase = (size_t)o0 + (lane << 2);

    for (int seg = 0; seg < 4; ++seg) {
        if (tq == seg) {
            double V[4], I[4];
            if (seg == 0) {
#pragma unroll
                for (int u = 0; u < 4; ++u) { V[u] = 0.0; I[u] = 0.0; }
            } else {
#pragma unroll
                for (int u = 0; u < 4; ++u) {
                    const double2 h = hand[hbase + u];
                    V[u] = h.x; I[u] = h.y;
                }
            }
#pragma unroll
            for (int tt = 0; tt < 5; ++tt) {
                const int t = seg * 5 + tt;
                float4 s;
                float* sp = &s.x;
#pragma unroll
                for (int u = 0; u < 4; ++u) {
                    V[u] = A_M * V[u] + DTM * I[u];
                    float sv = 0.0f;
                    if (V[u] >= 1.0) { sv = 1.0f; V[u] = 0.0; }
                    sp[u] = sv;
                    I[u] = A_S * I[u] + acc[tt][u];
                }
                *reinterpret_cast<float4*>(
                    out + ((size_t)t * BATCH + b) * DIM + obase) = s;
            }
            if (seg < 3) {
#pragma unroll
                for (int u = 0; u < 4; ++u)
                    hand[hbase + u] = make_double2(V[u], I[u]);
            }
        }
        __syncthreads();
    }
}

// ============================== host ==============================

extern "C" void kernel_launch(void* const* d_in, const int* in_sizes, int n_in,
                              void* d_out, int out_size, void* d_ws, size_t ws_size,
                              hipStream_t stream) {
    const float* x = (const float*)d_in[0];   // [20, 512, 2048] spikes
    const float* W = (const float*)d_in[1];   // [2048, 2048]
    float* out = (float*)d_out;               // [20, 512, 2048]
    char* wsb = (char*)d_ws;

    // choose the largest o-chunk whose int16 C planes fit in ws
    // need(no) = C_OFF + 4 * 10240 * no * 2 bytes
    int no = 0, shift = 0;
    if      (ws_size >= C_OFF + 81920ULL * 2048) { no = 2048; shift = 9; }
    else if (ws_size >= C_OFF + 81920ULL * 1024) { no = 1024; shift = 8; }
    else if (ws_size >= C_OFF + 81920ULL * 512)  { no = 512;  shift = 7; }
    else if (ws_size >= C_OFF + 81920ULL * 256)  { no = 256;  shift = 6; }
    else if (ws_size >= C_OFF + 81920ULL * 128)  { no = 128;  shift = 5; }

    if (no) {
        // exact i8-MFMA path (R25 = R19 gemm + fused prep; single-shot at no=2048)
        prep_xw_kernel<<<3072, 256, 0, stream>>>(x, W, wsb);
        short* cp = (short*)(wsb + C_OFF);
        const int ntc_cnt = no / 128;
        for (int nt0 = 0; nt0 < 16; nt0 += ntc_cnt) {
            gemm_i8_kernel<<<40 * ntc_cnt * 4, 512, 0, stream>>>(
                (const char*)wsb, cp, nt0, ntc_cnt, no);
            lif_kernel<<<no / 2, 256, 0, stream>>>(
                (const short*)cp, out, nt0 * 128, no, shift);
        }
    } else {
        // fallback: R10 sparse-gather pipeline (known-good, 580 us)
        float* WT = (float*)d_ws;
        dim3 tb(256);
        dim3 tg(DIM / 64, DIM / 64);
        transpose_kernel<<<tg, tb, 0, stream>>>(W, WT);
        const int grid = (BATCH / B_TILE) * (DIM / O_TILE);
        snn_lif_kernel<<<grid, NT, 0, stream>>>(x, WT, out);
    }
}